// Round 2
// baseline (458.400 us; speedup 1.0000x reference)
//
#include <hip/hip_runtime.h>

// LGA (GANet Local Guided Aggregation), radius=2, K=5.
// in1: [N=4, C=32, H=384, W=768] f32
// in2: [N=4, 25,   H=384, W=768] f32 (per-pixel taps, shared across C)
// out: [N, C, H, W] f32
//
// R1: barrier-free, LDS-free. Thread owns 4 consecutive pixels and keeps its
// 25 per-pixel tap weights (25x float4) in registers across the channel loop
// (in2 read exactly once). Per channel, the 5x8 in1 window is read straight
// from global as b64+b128+b64 per row (naturally aligned, zero waste); the
// 25x spatial reuse across neighboring threads is served by L1 (block tile
// ~8KB << 32KB L1). 15 independent loads per channel issue back-to-back, no
// __syncthreads anywhere -> latency hidden by vmcnt pipelining + 3 waves/SIMD.
// Waves align exactly with image rows (192 pixel-groups/row = 3 waves), so
// row predicates are wave-uniform; only edge lanes diverge on L/R loads.

#define N_DIM 4
#define C_DIM 32
#define H_DIM 384
#define W_DIM 768
#define HW (H_DIM * W_DIM)

__global__ __launch_bounds__(256, 3)
void lga_kernel(const float* __restrict__ in1,
                const float* __restrict__ in2,
                float* __restrict__ out) {
    const int wave = (int)((blockIdx.x * blockDim.x + threadIdx.x) >> 6);
    const int lane = threadIdx.x & 63;
    // 3 waves per image row (W/4 = 192 pixel-groups, 64 lanes each)
    const int rw   = wave % 3;
    const int hrow = (wave / 3) % H_DIM;
    const int n    = wave / (3 * H_DIM);
    const int wb   = rw * 256 + 4 * lane;   // first of this thread's 4 cols

    // ---- 25 per-pixel tap weights, resident across the whole c-loop ----
    float4 wt[25];
    const float* wsrc = in2 + (size_t)n * 25 * HW + (size_t)hrow * W_DIM + wb;
#pragma unroll
    for (int t = 0; t < 25; ++t)
        wt[t] = *(const float4*)(wsrc + (size_t)t * HW);

    const bool lok = (wb != 0);             // left halo in-row?
    const bool rko = (wb != W_DIM - 4);     // right halo in-row?
    bool rvalid[5];
#pragma unroll
    for (int i = 0; i < 5; ++i)
        rvalid[i] = (unsigned)(hrow - 2 + i) < (unsigned)H_DIM;

    const float* src = in1 + (size_t)n * C_DIM * HW + (size_t)hrow * W_DIM + wb;
    float*       dst = out + (size_t)n * C_DIM * HW + (size_t)hrow * W_DIM + wb;

    for (int c = 0; c < C_DIM; ++c) {
        // ---- issue all 15 loads for this channel, then compute ----
        float win[5][8];
#pragma unroll
        for (int i = 0; i < 5; ++i) {
            const float* p = src + (i - 2) * W_DIM;
            float2 L = make_float2(0.f, 0.f);
            float2 R = make_float2(0.f, 0.f);
            float4 M = make_float4(0.f, 0.f, 0.f, 0.f);
            if (rvalid[i]) {
                M = *(const float4*)p;                       // cols wb..wb+3 (16B aligned)
                if (lok) L = *(const float2*)(p - 2);        // cols wb-2..wb-1 (8B aligned)
                if (rko) R = *(const float2*)(p + 4);        // cols wb+4..wb+5 (8B aligned)
            }
            win[i][0] = L.x; win[i][1] = L.y;
            win[i][2] = M.x; win[i][3] = M.y; win[i][4] = M.z; win[i][5] = M.w;
            win[i][6] = R.x; win[i][7] = R.y;
        }

        float a0 = 0.f, a1 = 0.f, a2 = 0.f, a3 = 0.f;
#pragma unroll
        for (int i = 0; i < 5; ++i) {
#pragma unroll
            for (int j = 0; j < 5; ++j) {
                const float4 wv = wt[5 * i + j];
                a0 += wv.x * win[i][j + 0];
                a1 += wv.y * win[i][j + 1];
                a2 += wv.z * win[i][j + 2];
                a3 += wv.w * win[i][j + 3];
            }
        }

        *(float4*)dst = make_float4(a0, a1, a2, a3);
        src += HW;
        dst += HW;
    }
}

extern "C" void kernel_launch(void* const* d_in, const int* in_sizes, int n_in,
                              void* d_out, int out_size, void* d_ws, size_t ws_size,
                              hipStream_t stream) {
    const float* in1 = (const float*)d_in[0];
    const float* in2 = (const float*)d_in[1];
    float* out = (float*)d_out;
    // one thread per 4-pixel group: 4*384*192 = 294912 threads = 1152 blocks
    const int total_threads = N_DIM * H_DIM * (W_DIM / 4);
    lga_kernel<<<total_threads / 256, 256, 0, stream>>>(in1, in2, out);
}